// Round 12
// baseline (97888.550 us; speedup 1.0000x reference)
//
#include <hip/hip_runtime.h>
#include <cstddef>

#define T_ 1024
#define B_ 64
#define D_ 256
#define L_ 1024
#define DC_ 256
#define H_ 256
#define A_ 256
#define G3 768
#define LQ 256   // L_/4 per block
#define NBLK 4   // blocks per batch

typedef unsigned int uint2v __attribute__((ext_vector_type(2)));
typedef float float4v __attribute__((ext_vector_type(4)));
typedef float float2v __attribute__((ext_vector_type(2)));
typedef unsigned short ushort4v __attribute__((ext_vector_type(4)));

__device__ __forceinline__ float bflo(unsigned int w) { return __uint_as_float(w << 16); }
__device__ __forceinline__ float bfhi(unsigned int w) { return __uint_as_float(w & 0xffff0000u); }
__device__ __forceinline__ unsigned short f2bf(float f) {
  unsigned int x = __float_as_uint(f);
  return (unsigned short)((x + 0x7fffu + ((x >> 16) & 1u)) >> 16);
}
__device__ __forceinline__ float fast_tanh(float xx) {
  float e = __expf(2.0f * xx);
  return 1.0f - 2.0f / (e + 1.0f);
}
__device__ __forceinline__ float sigmoidf_(float xx) {
  return 1.0f / (1.0f + __expf(-xx));
}
__device__ __forceinline__ void st_agent_f(float* p, float v) {
  __hip_atomic_store(p, v, __ATOMIC_RELAXED, __HIP_MEMORY_SCOPE_AGENT);
}
__device__ __forceinline__ float ld_agent_f(const float* p) {
  return __hip_atomic_load(p, __ATOMIC_RELAXED, __HIP_MEMORY_SCOPE_AGENT);
}
__device__ __forceinline__ void group_arrive(unsigned int* ctrb) {
  __syncthreads();
  if (threadIdx.x == 0) {
    __hip_atomic_fetch_add(ctrb, 1u, __ATOMIC_RELAXED, __HIP_MEMORY_SCOPE_AGENT);
  }
}
__device__ __forceinline__ void group_wait(unsigned int* ctrb, unsigned int target) {
  if (threadIdx.x == 0) {
    while (__hip_atomic_load(ctrb, __ATOMIC_RELAXED, __HIP_MEMORY_SCOPE_AGENT) < target) {
      __builtin_amdgcn_s_sleep(2);
    }
  }
  __syncthreads();
}

__global__ void f2bf_kernel(const float* __restrict__ src,
                            unsigned short* __restrict__ dst, int n) {
  int i = (blockIdx.x * blockDim.x + threadIdx.x) * 4;
  if (i < n) {
    float4 v = *(const float4*)(src + i);
    ushort4 o;
    o.x = f2bf(v.x); o.y = f2bf(v.y); o.z = f2bf(v.z); o.w = f2bf(v.w);
    *(ushort4*)(dst + i) = o;
  }
}

__global__ __launch_bounds__(1024) void encoder_kernel(
    const float* __restrict__ x, const int* __restrict__ lengths,
    const float* __restrict__ context, const int* __restrict__ ctx_lengths,
    const float* __restrict__ Wc,
    const unsigned short* __restrict__ wx_b, const unsigned short* __restrict__ wh_b,
    const float* __restrict__ v,
    const unsigned short* __restrict__ wih_b, const unsigned short* __restrict__ whh_b,
    const float* __restrict__ b_ih, const float* __restrict__ b_hh,
    const unsigned short* __restrict__ ctx_bf, float* __restrict__ out,
    float* __restrict__ cpart, unsigned int* __restrict__ ctr) {
  __shared__ __align__(16) unsigned short ctx_lds[A_ * LQ];  // 131072 B [a][l_local]
  __shared__ __align__(16) float scratch[4096];              // 16384 B
  __shared__ __align__(16) float xt_s[D_];
  __shared__ __align__(16) float h_s[H_];
  __shared__ __align__(16) float c_s[DC_];
  __shared__ float q_s[A_];
  __shared__ float pv_s[LQ];
  __shared__ float gatI[G3], gatH[G3];
  __shared__ float wsum_l[4];
  // ~158.7 KB -> 1 block/CU

  const int gb = blockIdx.x;
  const int b = gb >> 2, kb = gb & 3;  // R5 mapping
  const int tid = threadIdx.x;
  const int len = lengths[b];
  const int clen = ctx_lengths[b];
  const int lbase = kb * LQ;
  const float* ctxb = context + (size_t)b * L_ * DC_;
  const unsigned short* ctxbf_b = ctx_bf + (size_t)b * L_ * DC_;
  float* cpart_b = cpart + (size_t)b * 2 * NBLK * 264;  // [parity][kb][264]
  unsigned int* ctr_b = ctr + b * 32;

  const int p16 = tid >> 6, i64 = tid & 63;
  const int kq2 = (tid >= 384) ? 1 : 0;        // GRU k-group (tid<768)
  const int cj384 = tid - kq2 * 384;           // col-pair index, CORRECT mod-384

  if (tid < 256) { h_s[tid] = 0.0f; q_s[tid] = 0.0f; }
  float vreg[16];
#pragma unroll
  for (int i = 0; i < 16; ++i) vreg[i] = v[p16 * 16 + i];
  float breg_i = 0.f, breg_h = 0.f;
  if (tid < G3) { breg_i = b_ih[tid]; breg_h = b_hh[tid]; }
  __syncthreads();

  // ---- prologue: in-block projection -> ctx_lds[a][l_local] (bf16) ----
  {
    const int a = tid & 255, lq4 = tid >> 8;
    for (int tl = 0; tl < 16; ++tl) {
      for (int idx = tid; idx < 4096; idx += 1024) {
        int r = idx >> 8, d = idx & 255;
        scratch[d * 16 + r] = ctxb[(size_t)(lbase + tl * 16 + r) * DC_ + d];
      }
      __syncthreads();
      float a0 = 0.f, a1 = 0.f, a2 = 0.f, a3 = 0.f;
#pragma unroll 4
      for (int d = 0; d < 256; ++d) {
        float w = Wc[(size_t)d * A_ + a];
        const float* ps = &scratch[d * 16 + lq4 * 4];
        a0 += ps[0] * w; a1 += ps[1] * w; a2 += ps[2] * w; a3 += ps[3] * w;
      }
      int l0 = tl * 16 + lq4 * 4;
      ushort4v o; o.x = f2bf(a0); o.y = f2bf(a1); o.z = f2bf(a2); o.w = f2bf(a3);
      *(ushort4v*)&ctx_lds[a * LQ + l0] = o;
      __syncthreads();
    }
  }

  for (int t = 0; t < len; ++t) {
    float* cpart_par = cpart_b + (size_t)(t & 1) * NBLK * 264;
    float* cpart_my = cpart_par + kb * 264;

    // ---- xt
    if (tid < 64) {
      *(float4v*)&xt_s[tid * 4] =
          *(const float4v*)&x[((size_t)t * B_ + b) * D_ + tid * 4];
    }
    __syncthreads();

    // ---- q[a] = xt@Wx + h@Wh (full, redundant; weights L2-hot)
    {
      const int a0 = i64 * 4, k0 = p16 * 16;
      float4v acc = {0.f, 0.f, 0.f, 0.f};
#pragma unroll
      for (int k = k0; k < k0 + 16; ++k) {
        float xv = xt_s[k];
        uint2v w = *(const uint2v*)(wx_b + (size_t)k * A_ + a0);
        acc.x += xv * bflo(w.x); acc.y += xv * bfhi(w.x);
        acc.z += xv * bflo(w.y); acc.w += xv * bfhi(w.y);
      }
#pragma unroll
      for (int k = k0; k < k0 + 16; ++k) {
        float hv = h_s[k];
        uint2v w = *(const uint2v*)(wh_b + (size_t)k * A_ + a0);
        acc.x += hv * bflo(w.x); acc.y += hv * bfhi(w.x);
        acc.z += hv * bflo(w.y); acc.w += hv * bfhi(w.y);
      }
      *(float4v*)&scratch[tid * 4] = acc;
    }
    __syncthreads();
    if (tid < 256) {
      float q = 0.f;
#pragma unroll
      for (int p = 0; p < 16; ++p) q += scratch[p * 256 + tid];
      q_s[tid] = q;
    }
    __syncthreads();

    // ---- scores from LDS: (p16,i64): 4 l's, a-strip 16
    {
      const int ll0 = i64 * 4;
      float4v acc = {0.f, 0.f, 0.f, 0.f};
      if (lbase + ll0 < clen) {
        const unsigned short* basep = ctx_lds + p16 * 16 * LQ + ll0;
#pragma unroll 4
        for (int aa = 0; aa < 16; ++aa) {
          uint2v w = *(const uint2v*)(basep + aa * LQ);
          float q = q_s[p16 * 16 + aa];
          float vv = vreg[aa];
          acc.x += vv * fast_tanh(bflo(w.x) + q);
          acc.y += vv * fast_tanh(bfhi(w.x) + q);
          acc.z += vv * fast_tanh(bflo(w.y) + q);
          acc.w += vv * fast_tanh(bfhi(w.y) + q);
        }
      }
      *(float4v*)&scratch[tid * 4] = acc;
    }
    __syncthreads();
    // ---- finalize scores -> exp (no max shift: |score| <= ||v||_1), wave sums
    if (tid < 256) {
      float s = 0.f;
#pragma unroll
      for (int p = 0; p < 16; ++p) s += scratch[p * 256 + tid];
      int lg = lbase + tid;
      float e = (lg < clen) ? __expf(s) : 0.f;
      pv_s[tid] = e;
      float sm = e;
#pragma unroll
      for (int off = 32; off; off >>= 1) sm += __shfl_xor(sm, off);
      if ((tid & 63) == 0) wsum_l[tid >> 6] = sm;
    }
    __syncthreads();

    // ---- c-partials from GLOBAL bf16 context (clen-capped)
    {
      const int d0 = i64 * 4;
      const int lmax = min(LQ, max(0, clen - lbase));
      const int l0 = p16 * 16, l1 = min(l0 + 16, lmax);
      float4v acc = {0.f, 0.f, 0.f, 0.f};
      for (int l = l0; l < l1; ++l) {
        float pv = pv_s[l];
        uint2v w = *(const uint2v*)(ctxbf_b + (size_t)(lbase + l) * DC_ + d0);
        acc.x += pv * bflo(w.x); acc.y += pv * bfhi(w.x);
        acc.z += pv * bflo(w.y); acc.w += pv * bfhi(w.y);
      }
      *(float4v*)&scratch[tid * 4] = acc;
    }
    __syncthreads();
    if (tid < 256) {
      float cp = 0.f;
#pragma unroll
      for (int p = 0; p < 16; ++p) cp += scratch[p * 256 + tid];
      st_agent_f(&cpart_my[tid], cp);
    }
    if (tid == 0) {
      st_agent_f(&cpart_my[256], wsum_l[0] + wsum_l[1] + wsum_l[2] + wsum_l[3]);
    }
    group_arrive(ctr_b);  // the ONLY sync per step; hidden under GRU phase A

    // ---- GRU phase A (c-independent, FULL 768 cols): gi_x and gh partials
    if (tid < 768) {
      const int r0 = kq2 * 128;
      float a0 = 0.f, a1 = 0.f, h0 = 0.f, h1 = 0.f;
#pragma unroll 8
      for (int i = 0; i < 128; ++i) {
        float zk = xt_s[r0 + i];
        unsigned int wi = *(const unsigned int*)(wih_b + (size_t)(r0 + i) * G3 + 2 * cj384);
        a0 += zk * bflo(wi); a1 += zk * bfhi(wi);
        float hv = h_s[r0 + i];
        unsigned int wh = *(const unsigned int*)(whh_b + (size_t)(r0 + i) * G3 + 2 * cj384);
        h0 += hv * bflo(wh); h1 += hv * bfhi(wh);
      }
      *(float2v*)&scratch[kq2 * 768 + 2 * cj384] = float2v{a0, a1};
      *(float2v*)&scratch[1536 + kq2 * 768 + 2 * cj384] = float2v{h0, h1};
    }
    __syncthreads();
    if (tid < G3) {
      gatI[tid] = breg_i + scratch[tid] + scratch[768 + tid];
      gatH[tid] = breg_h + scratch[1536 + tid] + scratch[1536 + 768 + tid];
    }
    group_wait(ctr_b, 4u * t + 4u);  // sync wait (likely already satisfied)

    // ---- assemble c (from this step's parity buffer)
    {
      float cc = 0.f;
      if (tid < 256) {
#pragma unroll
        for (int k2 = 0; k2 < 4; ++k2) cc += ld_agent_f(cpart_par + k2 * 264 + tid);
      } else if (tid < 260) {
        wsum_l[tid - 256] = ld_agent_f(cpart_par + (tid - 256) * 264 + 256);
      }
      __syncthreads();
      if (tid < 256) {
        c_s[tid] = cc / (wsum_l[0] + wsum_l[1] + wsum_l[2] + wsum_l[3]);
      }
    }
    __syncthreads();

    // ---- GRU phase B: gi_c partials (rows 256..511 of W_ih with c)
    if (tid < 768) {
      const int r0 = kq2 * 128;
      float b0 = 0.f, b1 = 0.f;
#pragma unroll 8
      for (int i = 0; i < 128; ++i) {
        float zk = c_s[r0 + i];
        unsigned int wi =
            *(const unsigned int*)(wih_b + (size_t)(256 + r0 + i) * G3 + 2 * cj384);
        b0 += zk * bflo(wi); b1 += zk * bfhi(wi);
      }
      *(float2v*)&scratch[kq2 * 768 + 2 * cj384] = float2v{b0, b1};
    }
    __syncthreads();
    if (tid < G3) {
      gatI[tid] += scratch[tid] + scratch[768 + tid];
    }
    __syncthreads();

    // ---- gates + h update (FULL h locally; no exchange)
    if (tid < 256) {
      float r = sigmoidf_(gatI[tid] + gatH[tid]);
      float u = sigmoidf_(gatI[256 + tid] + gatH[256 + tid]);
      float n = fast_tanh(gatI[512 + tid] + r * gatH[512 + tid]);
      float hn = u * h_s[tid] + (1.0f - u) * n;
      h_s[tid] = hn;
      if ((tid >> 6) == kb) {
        __builtin_nontemporal_store(hn, &out[((size_t)t * B_ + b) * H_ + tid]);
      }
    }
    __syncthreads();
  }

  // zero-fill masked timesteps: own 64-col slice
  {
    const int n = (T_ - len) * 64;
    for (int idx = tid; idx < n; idx += 1024) {
      int tt = len + (idx >> 6);
      int ii = idx & 63;
      __builtin_nontemporal_store(0.0f, &out[((size_t)tt * B_ + b) * H_ + kb * 64 + ii]);
    }
  }
  // h_final: own slice
  if (tid < 64) {
    out[(size_t)T_ * B_ * H_ + (size_t)b * H_ + kb * 64 + tid] = h_s[kb * 64 + tid];
  }
}

extern "C" void kernel_launch(void* const* d_in, const int* in_sizes, int n_in,
                              void* d_out, int out_size, void* d_ws, size_t ws_size,
                              hipStream_t stream) {
  const float* x = (const float*)d_in[0];
  const int* lengths = (const int*)d_in[1];
  const float* context = (const float*)d_in[2];
  const int* ctx_lengths = (const int*)d_in[3];
  const float* Wc = (const float*)d_in[4];
  const float* Wx = (const float*)d_in[5];
  const float* Wh = (const float*)d_in[6];
  const float* v = (const float*)d_in[7];
  const float* W_ih = (const float*)d_in[8];
  const float* W_hh = (const float*)d_in[9];
  const float* b_ih = (const float*)d_in[10];
  const float* b_hh = (const float*)d_in[11];
  float* out = (float*)d_out;

  char* w = (char*)d_ws;
  unsigned short* ctx_bf = (unsigned short*)w;                      // 33,554,432 B
  unsigned short* wx_b = (unsigned short*)(w + 33554432);           // 131,072 B
  unsigned short* wh_b = (unsigned short*)(w + 33685504);           // 131,072 B
  unsigned short* wih_b = (unsigned short*)(w + 33816576);          // 786,432 B
  unsigned short* whh_b = (unsigned short*)(w + 34603008);          // 393,216 B
  float* cpart = (float*)(w + 34996224);                            // 540,672 B (2 par)
  unsigned int* ctr = (unsigned int*)(w + 35536896);                // 8,192 B

  hipMemsetAsync(ctr, 0, 8192, stream);
  hipLaunchKernelGGL(f2bf_kernel, dim3(16384), dim3(256), 0, stream,
                     context, ctx_bf, B_ * L_ * DC_);
  hipLaunchKernelGGL(f2bf_kernel, dim3(64), dim3(256), 0, stream, Wx, wx_b, D_ * A_);
  hipLaunchKernelGGL(f2bf_kernel, dim3(64), dim3(256), 0, stream, Wh, wh_b, H_ * A_);
  hipLaunchKernelGGL(f2bf_kernel, dim3(384), dim3(256), 0, stream,
                     W_ih, wih_b, (D_ + DC_) * G3);
  hipLaunchKernelGGL(f2bf_kernel, dim3(192), dim3(256), 0, stream,
                     W_hh, whh_b, H_ * G3);
  hipLaunchKernelGGL(encoder_kernel, dim3(B_ * NBLK), dim3(1024), 0, stream,
                     x, lengths, context, ctx_lengths, Wc, wx_b, wh_b, v,
                     wih_b, whh_b, b_ih, b_hh, ctx_bf, out, cpart, ctr);
}